// Round 9
// baseline (222.410 us; speedup 1.0000x reference)
//
#include <hip/hip_runtime.h>

#define NLINKS 4096
#define CHUNKS 4          // fvec4 per thread: 4 * 4 * 256 threads = 4096 elems
#define RPB 4             // rows per block (2-deep register ping-pong)

typedef float fvec4 __attribute__((ext_vector_type(4)));

constexpr float kPmax = 0.1f;
constexpr float kBudget = 100.0f;
constexpr int kGrid = 5;          // tau grid points evaluated in pass A
constexpr float kBmax = 16.0f;    // constant upper bracket: g(16)=0 always
constexpr int kFallbackIters = 8; // Illinois iters when tau is outside grid

// clip(x,0,PMAX) in ONE VALU op: v_med3_f32
__device__ __forceinline__ float clip01(float x) {
  return __builtin_amdgcn_fmed3f(x, 0.0f, kPmax);
}

// Batched reduce: N independent sums share interleaved shuffle latency.
template <int N>
__device__ __forceinline__ void waveReduceSumN(float* x) {
#pragma unroll
  for (int m = 32; m >= 1; m >>= 1) {
    float t[N];
#pragma unroll
    for (int k = 0; k < N; ++k) t[k] = __shfl_xor(x[k], m, 64);
#pragma unroll
    for (int k = 0; k < N; ++k) x[k] += t[k];
  }
}

// NON-DRAINING block barrier (the r3 lesson, applied to barriers):
// __syncthreads() emits `s_waitcnt vmcnt(0) lgkmcnt(0)` and would drain the
// next row's prefetch loads at every reduce. We only need the LDS partial-sum
// writes ordered -> lgkmcnt(0) + raw s_barrier; global loads stay in flight.
__device__ __forceinline__ void ldsBarrier() {
  asm volatile("s_waitcnt lgkmcnt(0)" ::: "memory");
  __builtin_amdgcn_s_barrier();
  asm volatile("" ::: "memory");
}

struct SharedBufs {
  // Parity-duplicated reduce buffers: row with parity P uses set P. One
  // barrier per site is race-free: set-P read (row r) and set-P rewrite
  // (row r+2) are always separated by >=1 barrier of row r+1.
  float A[2][4][kGrid + 1];  // pass A partials per wave
  float N[2][4][2];          // Newton partials per wave
  float F[4];                // fallback (rare; uses __syncthreads)
};

__device__ __forceinline__ void loadRow(const float* __restrict__ raw, int row,
                                        int tid, fvec4 (&v)[CHUNKS]) {
  const fvec4* rp = (const fvec4*)(raw + (size_t)row * NLINKS);
#pragma unroll
  for (int j = 0; j < CHUNKS; ++j)
    v[j] = __builtin_nontemporal_load(&rp[tid + 256 * j]);
}

// ROUNDS 0-8 LESSON LEDGER:
//  r1/r2: per-WAVE register double-buffer (128 data VGPRs) always spills.
//  r3/r4: persistent waves + LDS prefetch phase-lock -> 94 us; counted vmcnt
//         changed nothing (store drain was not the cost).
//  r6:    3-pass streaming, occ 27.6%: still 93 us -> per-row critical path.
//  r7:    one row per BLOCK: proj ~70 us. Win, but residual remains.
//  r8:    pass-A VALU cut 27->17 ops/elem: NO change -> VALU off the
//         critical path. Residual = load-issue holes: during each block's
//         compute+barrier+store span (~2k cyc) no loads are issued, and
//         co-resident blocks align phases (convoy). ~3.8 TB/s vs 6.3.
//  THIS ROUND: pipeline ROWS within a block. 4 rows/block, A/B register
//  ping-pong (32 data VGPRs - 4x smaller than r1's spiller): every
//  processRow has the next row's 16 global_load_dwordx4 in flight. Hot-path
//  barriers are non-draining (lgkmcnt-only) so prefetch survives them.
template <int P>
__device__ __forceinline__ void processRow(const fvec4 (&v)[CHUNKS],
                                           float* __restrict__ out, int row,
                                           int tid, int wave, int lane,
                                           SharedBufs& sh) {
  fvec4* op = (fvec4*)(out + (size_t)row * NLINKS);

  // tau ~= 0.641 +- 0.02 for this problem's N(0,1) rows; points span +-5
  // sigma. Outside -> Illinois fallback (correct, ~never taken).
  const float pts[kGrid] = {0.54f, 0.60f, 0.65f, 0.70f, 0.76f};

  // ---- Pass A: g(0)=fs and g(pts[i]) ----
  float s[kGrid + 1];
#pragma unroll
  for (int k = 0; k <= kGrid; ++k) s[k] = 0.f;
#pragma unroll
  for (int j = 0; j < CHUNKS; ++j) {
#pragma unroll
    for (int c = 0; c < 4; ++c) {
      const float x = v[j][c];
      s[0] += clip01(x);
#pragma unroll
      for (int i = 0; i < kGrid; ++i) s[i + 1] += clip01(x - pts[i]);
    }
  }
  waveReduceSumN<kGrid + 1>(s);
  if (lane == 0) {
#pragma unroll
    for (int k = 0; k <= kGrid; ++k) sh.A[P][wave][k] = s[k];
  }
  ldsBarrier();
#pragma unroll
  for (int k = 0; k <= kGrid; ++k)
    s[k] = (sh.A[P][0][k] + sh.A[P][1][k]) + (sh.A[P][2][k] + sh.A[P][3][k]);
  const float fs = s[0];

  if (fs <= kBudget) {  // feasible: clip only (block-uniform branch)
#pragma unroll
    for (int j = 0; j < CHUNKS; ++j) {
      fvec4 o;
#pragma unroll
      for (int c = 0; c < 4; ++c) o[c] = clip01(v[j][c]);
      __builtin_nontemporal_store(o, &op[tid + 256 * j]);
    }
    return;
  }

  // Select bracketing segment. g is decreasing: g(0)=fs>B, g(kBmax)=0.
  float a = 0.f, ga = fs, b = kBmax, gb = 0.f;
  bool need_iter = true;
  if (s[1] < kBudget) {                    // tau < pts[0]
    a = 0.f; ga = fs; b = pts[0]; gb = s[1];
  } else if (s[kGrid] > kBudget) {         // tau > pts[last]
    a = pts[kGrid - 1]; ga = s[kGrid]; b = kBmax; gb = 0.f;
  } else {
#pragma unroll
    for (int i = 0; i < kGrid - 1; ++i) {
      if (s[i + 1] >= kBudget && s[i + 2] <= kBudget) {
        a = pts[i]; ga = s[i + 1]; b = pts[i + 1]; gb = s[i + 2];
        need_iter = false;
        break;
      }
    }
  }

  if (need_iter) {  // rare: Illinois false position (block-uniform); plain
                    // __syncthreads here is fine - path ~never taken.
    int side = 0;
#pragma unroll 1
    for (int it = 0; it < kFallbackIters; ++it) {
      const float denom = gb - ga;
      float t = (denom != 0.f) ? b - (gb - kBudget) * (b - a) / denom
                               : 0.5f * (a + b);
      if (!(t > a && t < b)) t = 0.5f * (a + b);
      float s0 = 0.f, s1 = 0.f, s2 = 0.f, s3 = 0.f;
#pragma unroll
      for (int j = 0; j < CHUNKS; ++j) {
        s0 += clip01(v[j].x - t);
        s1 += clip01(v[j].y - t);
        s2 += clip01(v[j].z - t);
        s3 += clip01(v[j].w - t);
      }
      float g = (s0 + s1) + (s2 + s3);
      waveReduceSumN<1>(&g);
      if (lane == 0) sh.F[wave] = g;
      __syncthreads();
      g = (sh.F[0] + sh.F[1]) + (sh.F[2] + sh.F[3]);
      __syncthreads();  // sh.F rewritten next iteration
      if (g > kBudget) {
        a = t; ga = g;
        if (side == 1) gb = kBudget + 0.5f * (gb - kBudget);
        side = 1;
      } else {
        b = t; gb = g;
        if (side == -1) ga = kBudget + 0.5f * (ga - kBudget);
        side = -1;
      }
    }
  }

  // False position within the (locally linear) segment.
  const float dd = ga - gb;
  float tau0 = (dd != 0.f) ? a + (ga - kBudget) * (b - a) / dd : 0.5f * (a + b);
  if (!(tau0 >= a && tau0 <= b)) tau0 = 0.5f * (a + b);

  // ---- Pass B: Newton correction (exact within the linear segment) ----
  float gn[2] = {0.f, 0.f};  // gn[0]=g(tau0), gn[1]=n_active
#pragma unroll
  for (int j = 0; j < CHUNKS; ++j) {
#pragma unroll
    for (int c = 0; c < 4; ++c) {
      const float t = v[j][c] - tau0;
      gn[0] += clip01(t);
      gn[1] += (t > 0.f && t < kPmax) ? 1.f : 0.f;
    }
  }
  waveReduceSumN<2>(gn);
  if (lane == 0) {
    sh.N[P][wave][0] = gn[0];
    sh.N[P][wave][1] = gn[1];
  }
  ldsBarrier();
  gn[0] = (sh.N[P][0][0] + sh.N[P][1][0]) + (sh.N[P][2][0] + sh.N[P][3][0]);
  gn[1] = (sh.N[P][0][1] + sh.N[P][1][1]) + (sh.N[P][2][1] + sh.N[P][3][1]);
  const float tau = tau0 + (gn[0] - kBudget) / fmaxf(gn[1], 1.0f);

  // ---- Pass C: output from registers ----
#pragma unroll
  for (int j = 0; j < CHUNKS; ++j) {
    fvec4 o;
#pragma unroll
    for (int c = 0; c < 4; ++c) o[c] = clip01(v[j][c] - tau);
    __builtin_nontemporal_store(o, &op[tid + 256 * j]);
  }
}

__global__ __launch_bounds__(256) void proj_kernel(
    const float* __restrict__ raw, float* __restrict__ out, int rows) {
  __shared__ SharedBufs sh;
  const int tid = threadIdx.x;
  const int wave = tid >> 6;
  const int lane = tid & 63;
  const int r0 = blockIdx.x * RPB;
  if (r0 >= rows) return;

  fvec4 vA[CHUNKS], vB[CHUNKS];
  const bool h1 = r0 + 1 < rows, h2 = r0 + 2 < rows, h3 = r0 + 3 < rows;

  // 2-deep ping-pong over 4 rows: every processRow has the NEXT row's loads
  // in flight (issued in the preceding gap; the memory-clobber barriers pin
  // them there - they can neither hoist above the previous processRow nor
  // sink below the next one's first barrier).
  loadRow(raw, r0, tid, vA);
  if (h1) loadRow(raw, r0 + 1, tid, vB);
  processRow<0>(vA, out, r0, tid, wave, lane, sh);
  if (h2) loadRow(raw, r0 + 2, tid, vA);
  if (h1) processRow<1>(vB, out, r0 + 1, tid, wave, lane, sh);
  if (h3) loadRow(raw, r0 + 3, tid, vB);
  if (h2) processRow<0>(vA, out, r0 + 2, tid, wave, lane, sh);
  if (h3) processRow<1>(vB, out, r0 + 3, tid, wave, lane, sh);
}

extern "C" void kernel_launch(void* const* d_in, const int* in_sizes, int n_in,
                              void* d_out, int out_size, void* d_ws, size_t ws_size,
                              hipStream_t stream) {
  const float* raw = (const float*)d_in[0];
  float* out = (float*)d_out;
  const int rows = in_sizes[0] / NLINKS;
  const int blocks = (rows + RPB - 1) / RPB;  // 2048 blocks of 4 rows
  hipLaunchKernelGGL(proj_kernel, dim3(blocks), dim3(256), 0, stream,
                     raw, out, rows);
}